// Round 10
// baseline (127.054 us; speedup 1.0000x reference)
//
#include <hip/hip_runtime.h>
#include <math.h>

#define BSZ 4096
#define DIM 256
// 20 * log2(e): rows are pre-scaled by sqrt(20*log2e)/||row|| so the MFMA
// emits u = score*log2e; exp2(u - SC20L2E) == exp(score - 20) exactly.
#define SC20L2E 28.853900817779268f

#if __has_builtin(__builtin_amdgcn_exp2f)
#define EXP2F(x) __builtin_amdgcn_exp2f(x)
#else
#define EXP2F(x) exp2f(x)
#endif

typedef int   intx4    __attribute__((ext_vector_type(4)));
typedef int   intx8    __attribute__((ext_vector_type(8)));
typedef float floatx16 __attribute__((ext_vector_type(16)));

__device__ __forceinline__ void async_cp16(void* lds, const void* g) {
    __builtin_amdgcn_global_load_lds(
        (__attribute__((address_space(1))) unsigned int*)(unsigned long long)g,
        (__attribute__((address_space(3))) unsigned int*)lds,
        16, 0, 0);
}

// One wave per row index: load row r of all 4 matrices once.
// Outputs: fp8 e4m3 rows pre-scaled by sqrt(20*log2e)/||row||, fp32 diagonal
// scores for the 4 pairs; zeroes rowsum/colsum; inits out[0]=40 (const term).
__global__ __launch_bounds__(256)
void prep_kernel(const float* __restrict__ a0, const float* __restrict__ a1,
                 const float* __restrict__ a2, const float* __restrict__ a3,
                 unsigned char* __restrict__ f8, float* __restrict__ diag,
                 float* __restrict__ rowsum, float* __restrict__ colsum,
                 float* __restrict__ out) {
    const float* srcs[4] = {a0, a1, a2, a3};
    int w = threadIdx.x >> 6, lane = threadIdx.x & 63;
    int row = blockIdx.x * 4 + w;

    float4 v[4];
    float red[8];
    #pragma unroll
    for (int m = 0; m < 4; m++) {
        v[m] = ((const float4*)(srcs[m] + (size_t)row * DIM))[lane];
        red[m] = v[m].x * v[m].x + v[m].y * v[m].y + v[m].z * v[m].z + v[m].w * v[m].w;
    }
    // pair dots: (0,1) (0,2) (1,2) (1,3)
    red[4] = v[0].x * v[1].x + v[0].y * v[1].y + v[0].z * v[1].z + v[0].w * v[1].w;
    red[5] = v[0].x * v[2].x + v[0].y * v[2].y + v[0].z * v[2].z + v[0].w * v[2].w;
    red[6] = v[1].x * v[2].x + v[1].y * v[2].y + v[1].z * v[2].z + v[1].w * v[2].w;
    red[7] = v[1].x * v[3].x + v[1].y * v[3].y + v[1].z * v[3].z + v[1].w * v[3].w;

    #pragma unroll
    for (int i = 0; i < 8; i++) {
        #pragma unroll
        for (int s = 32; s; s >>= 1) red[i] += __shfl_xor(red[i], s, 64);
    }

    float rinv[4];
    #pragma unroll
    for (int m = 0; m < 4; m++) rinv[m] = rsqrtf(fmaxf(red[m], 1e-24f));

    const float sq = sqrtf(SC20L2E);
    #pragma unroll
    for (int m = 0; m < 4; m++) {
        float sc = sq * rinv[m];
        int pk = __builtin_amdgcn_cvt_pk_fp8_f32(v[m].x * sc, v[m].y * sc, 0, false);
        pk = __builtin_amdgcn_cvt_pk_fp8_f32(v[m].z * sc, v[m].w * sc, pk, true);
        ((unsigned int*)(f8 + (size_t)m * BSZ * DIM))[row * 64 + lane] = (unsigned int)pk;
    }

    if (lane == 0) {
        diag[0 * BSZ + row] = red[4] * 20.0f * rinv[0] * rinv[1];
        diag[1 * BSZ + row] = red[5] * 20.0f * rinv[0] * rinv[2];
        diag[2 * BSZ + row] = red[6] * 20.0f * rinv[1] * rinv[2];
        diag[3 * BSZ + row] = red[7] * 20.0f * rinv[1] * rinv[3];
    }
    if (blockIdx.x < 64) {
        int idx = blockIdx.x * 256 + threadIdx.x;
        rowsum[idx] = 0.f;
        colsum[idx] = 0.f;
        if (idx == 0) out[0] = 40.0f;   // + 20*4B/(2B) constant term
    }
}

// Epilogue for one 128x128 tile held as 2x2 MX 32x32 accumulators:
// exp2 (raw v_exp_f32), value-splitting butterfly row/col reductions, atomics.
// C/D layout (32x32): col = lane&31, row = (reg&3)+8*(reg>>2)+4*(lane>>5).
// Verified end-to-end in rounds 8/9 (absmax 0.0).
__device__ __forceinline__ void tile_epilogue(floatx16 (&acc)[2][2],
                                              float* __restrict__ rs,
                                              float* __restrict__ cs,
                                              int bi, int bj, int wm, int wn,
                                              int l5, int h) {
    #pragma unroll
    for (int i = 0; i < 2; i++)
        #pragma unroll
        for (int j = 0; j < 2; j++)
            #pragma unroll
            for (int r = 0; r < 16; r++)
                acc[i][j][r] = EXP2F(acc[i][j][r]);

    // Row sums: v[t], t = ti*16 + reg, reduced over the 32 l5-lanes via
    // 5-level value-splitting butterfly; lane l5 ends holding v[l5].
    float v[32];
    #pragma unroll
    for (int t = 0; t < 2; t++)
        #pragma unroll
        for (int r = 0; r < 16; r++)
            v[t * 16 + r] = acc[t][0][r] + acc[t][1][r];

    float u1[16];
    #pragma unroll
    for (int k = 0; k < 16; k++) {
        float snd = (l5 & 1) ? v[2 * k] : v[2 * k + 1];
        float got = __shfl_xor(snd, 1, 64);
        u1[k] = ((l5 & 1) ? v[2 * k + 1] : v[2 * k]) + got;
    }
    float u2[8];
    #pragma unroll
    for (int k = 0; k < 8; k++) {
        float snd = ((l5 >> 1) & 1) ? u1[2 * k] : u1[2 * k + 1];
        float got = __shfl_xor(snd, 2, 64);
        u2[k] = (((l5 >> 1) & 1) ? u1[2 * k + 1] : u1[2 * k]) + got;
    }
    float u3[4];
    #pragma unroll
    for (int k = 0; k < 4; k++) {
        float snd = ((l5 >> 2) & 1) ? u2[2 * k] : u2[2 * k + 1];
        float got = __shfl_xor(snd, 4, 64);
        u3[k] = (((l5 >> 2) & 1) ? u2[2 * k + 1] : u2[2 * k]) + got;
    }
    float u4[2];
    #pragma unroll
    for (int k = 0; k < 2; k++) {
        float snd = ((l5 >> 3) & 1) ? u3[2 * k] : u3[2 * k + 1];
        float got = __shfl_xor(snd, 8, 64);
        u4[k] = (((l5 >> 3) & 1) ? u3[2 * k + 1] : u3[2 * k]) + got;
    }
    {
        float snd = ((l5 >> 4) & 1) ? u4[0] : u4[1];
        float got = __shfl_xor(snd, 16, 64);
        float wr = (((l5 >> 4) & 1) ? u4[1] : u4[0]) + got;
        // lane l5 holds row-sum for t=l5: ti = l5>>4, reg = l5&15
        int reg = l5 & 15;
        int row = bi + wm * 64 + (l5 >> 4) * 32
                + (reg & 3) + 8 * (reg >> 2) + 4 * h;
        atomicAdd(&rs[row], wr);
    }

    // Col sums: c[tj] over both ti tiles' regs; reduce over h-halves.
    float c0 = 0.f, c1 = 0.f;
    #pragma unroll
    for (int t = 0; t < 2; t++)
        #pragma unroll
        for (int r = 0; r < 16; r++) {
            c0 += acc[t][0][r];
            c1 += acc[t][1][r];
        }
    {
        float snd = h ? c0 : c1;
        float got = __shfl_xor(snd, 32, 64);
        float cc = (h ? c1 : c0) + got;
        atomicAdd(&cs[bj + wn * 64 + h * 32 + l5], cc);
    }
}

// TWO 128x128 pair-tiles per block from 3 shared panels (staging-BW bound
// kernel: 2048 blocks x 48 KB = 100 MB staged vs 268 MB for 1-tile blocks).
// g = blockIdx.z: g=0 rows=anchor, cols={pos,rtext} (pairs 0,1);
//                 g=1 rows=pos,    cols={rtext,rvis} (pairs 2,3).
// K split in two 128-wide phases (3 x 16 KB panels/phase, 48 KB LDS).
// MX-scaled fp8 MFMA (unit E8M0 scales 0x7F): numerics identical to fp8.
// XOR chunk swizzle (8 chunks/row): addr = row*128 + (((c^row)&7)<<4);
// fragment addr = Q ^ (ks<<6) ^ 16, Q hoisted.
// A/B operand layout (32x32x64): row = lane&31, k = (lane>>5)*32 + byte.
// Accumulators init to -SC20L2E so the epilogue is a bare v_exp_f32.
// NOTE: no min-waves in launch_bounds -- round 7 showed forcing occupancy
// spills the 128-VGPR accumulator bank (48 VGPR + 192 MB scratch traffic).
__global__ __launch_bounds__(256)
void pair_scores_kernel(const unsigned char* __restrict__ f8,
                        float* __restrict__ rowsum,
                        float* __restrict__ colsum) {
    int g = blockIdx.z;
    const unsigned char* Xb  = f8 + (size_t)g * BSZ * DIM;        // row matrix
    const unsigned char* Y0b = f8 + (size_t)(g + 1) * BSZ * DIM;  // cols, pair 2g
    const unsigned char* Y1b = f8 + (size_t)(g + 2) * BSZ * DIM;  // cols, pair 2g+1
    float* rs0 = rowsum + (2 * g) * BSZ;
    float* cs0 = colsum + (2 * g) * BSZ;
    float* rs1 = rowsum + (2 * g + 1) * BSZ;
    float* cs1 = colsum + (2 * g + 1) * BSZ;

    __shared__ __align__(16) unsigned char smem[49152];

    int tid  = threadIdx.x;
    int lane = tid & 63;
    int w    = tid >> 6;
    int wm = w >> 1, wn = w & 1;
    int l5 = lane & 31, h = lane >> 5;
    int bi = blockIdx.x * 128, bj = blockIdx.y * 128;

    // Hoisted fragment bases (h<<5 folded; ks<<6 and ^16 at read time).
    unsigned qa[2], qb[2];
    #pragma unroll
    for (int t = 0; t < 2; t++) {
        int ra = wm * 64 + t * 32 + l5;
        int rb = wn * 64 + t * 32 + l5;
        qa[t] = (unsigned)(ra * 128 + ((ra & 7) << 4)) ^ (unsigned)(h << 5);
        qb[t] = (unsigned)(rb * 128 + ((rb & 7) << 4)) ^ (unsigned)(h << 5);
    }

    // Staging addresses (4 cp16/thread per panel per phase; phase1 = +128 B).
    const unsigned char* gX[4];
    const unsigned char* gY0[4];
    const unsigned char* gY1[4];
    unsigned ldsoff[4];
    #pragma unroll
    for (int i = 0; i < 4; i++) {
        int sb  = i * 256 + w * 64;     // wave-uniform chunk base
        int s   = sb + lane;
        int row = s >> 3;
        int kq  = (s ^ row) & 7;
        ldsoff[i] = (unsigned)(sb * 16);
        gX[i]  = Xb  + (size_t)(bi + row) * 256 + kq * 16;
        gY0[i] = Y0b + (size_t)(bj + row) * 256 + kq * 16;
        gY1[i] = Y1b + (size_t)(bj + row) * 256 + kq * 16;
    }

    floatx16 acc0[2][2], acc1[2][2];
    #pragma unroll
    for (int i = 0; i < 2; i++)
        #pragma unroll
        for (int j = 0; j < 2; j++)
            #pragma unroll
            for (int r = 0; r < 16; r++) {
                acc0[i][j][r] = -SC20L2E;
                acc1[i][j][r] = -SC20L2E;
            }

    #pragma unroll 1
    for (int ph = 0; ph < 2; ph++) {
        if (ph) __syncthreads();        // previous-phase LDS reads complete
        int ko = ph * 128;
        #pragma unroll
        for (int i = 0; i < 4; i++) {
            async_cp16(smem + ldsoff[i],         gX[i]  + ko);
            async_cp16(smem + 16384 + ldsoff[i], gY0[i] + ko);
            async_cp16(smem + 32768 + ldsoff[i], gY1[i] + ko);
        }
        __syncthreads();                // staging drained (vmcnt in barrier)

        #pragma unroll 1                // cap fragment liveness (no spill)
        for (int ks = 0; ks < 2; ks++) {
            const unsigned kx = (unsigned)(ks << 6);
            intx8 A[2], B[2];
            #pragma unroll
            for (int t = 0; t < 2; t++) {
                unsigned a0 = qa[t] ^ kx;
                intx4 lo = *(const intx4*)(smem + a0);
                intx4 hi = *(const intx4*)(smem + (a0 ^ 16u));
                A[t] = (intx8){lo[0], lo[1], lo[2], lo[3], hi[0], hi[1], hi[2], hi[3]};
            }
            #pragma unroll
            for (int t = 0; t < 2; t++) {
                unsigned b0 = 16384u + (qb[t] ^ kx);
                intx4 bl = *(const intx4*)(smem + b0);
                intx4 bh = *(const intx4*)(smem + (b0 ^ 16u));
                B[t] = (intx8){bl[0], bl[1], bl[2], bl[3], bh[0], bh[1], bh[2], bh[3]};
            }
            #pragma unroll
            for (int i = 0; i < 2; i++)
                #pragma unroll
                for (int j = 0; j < 2; j++)
                    acc0[i][j] = __builtin_amdgcn_mfma_scale_f32_32x32x64_f8f6f4(
                        A[i], B[j], acc0[i][j], 0, 0,
                        0, 0x7F7F7F7F, 0, 0x7F7F7F7F);
            #pragma unroll
            for (int t = 0; t < 2; t++) {
                unsigned b0 = 32768u + (qb[t] ^ kx);
                intx4 bl = *(const intx4*)(smem + b0);
                intx4 bh = *(const intx4*)(smem + (b0 ^ 16u));
                B[t] = (intx8){bl[0], bl[1], bl[2], bl[3], bh[0], bh[1], bh[2], bh[3]};
            }
            #pragma unroll
            for (int i = 0; i < 2; i++)
                #pragma unroll
                for (int j = 0; j < 2; j++)
                    acc1[i][j] = __builtin_amdgcn_mfma_scale_f32_32x32x64_f8f6f4(
                        A[i], B[j], acc1[i][j], 0, 0,
                        0, 0x7F7F7F7F, 0, 0x7F7F7F7F);
        }
    }

    tile_epilogue(acc0, rs0, cs0, bi, bj, wm, wn, l5, h);
    tile_epilogue(acc1, rs1, cs1, bi, bj, wm, wn, l5, h);
}

// 64 blocks: each thread one (pair,row) entry; wave-reduce then atomicAdd
// into out (prep pre-set out = 40, the 20*4B/(2B) constant).
__global__ __launch_bounds__(256)
void final_reduce_kernel(const float* __restrict__ rowsum,
                         const float* __restrict__ colsum,
                         const float* __restrict__ diag,
                         float* __restrict__ out) {
    int idx = blockIdx.x * 256 + threadIdx.x;
    float acc = 0.5f * (__logf(rowsum[idx]) + __logf(colsum[idx])) - diag[idx];
    #pragma unroll
    for (int s = 32; s; s >>= 1) acc += __shfl_xor(acc, s, 64);
    if ((threadIdx.x & 63) == 0)
        atomicAdd(out, acc * (1.0f / (2.0f * BSZ)));
}

extern "C" void kernel_launch(void* const* d_in, const int* in_sizes, int n_in,
                              void* d_out, int out_size, void* d_ws, size_t ws_size,
                              hipStream_t stream) {
    const float* in_anchor = (const float*)d_in[0];
    const float* in_pos    = (const float*)d_in[1];
    // d_in[2] (reference_anchor) intentionally unused, matching the reference.
    const float* in_rtext  = (const float*)d_in[3];
    const float* in_rvis   = (const float*)d_in[4];

    char* ws = (char*)d_ws;
    unsigned char* f8 = (unsigned char*)ws;                 // 4 * B * D fp8
    size_t f8_bytes = (size_t)4 * BSZ * DIM;
    float* rowsum = (float*)(ws + f8_bytes);                // 4 * B
    float* colsum = rowsum + 4 * BSZ;                       // 4 * B
    float* diag   = colsum + 4 * BSZ;                       // 4 * B

    prep_kernel<<<BSZ / 4, 256, 0, stream>>>(
        in_anchor, in_pos, in_rtext, in_rvis, f8, diag, rowsum, colsum,
        (float*)d_out);

    pair_scores_kernel<<<dim3(BSZ / 128, BSZ / 128, 2), 256, 0, stream>>>(
        f8, rowsum, colsum);

    final_reduce_kernel<<<64, 256, 0, stream>>>(
        rowsum, colsum, diag, (float*)d_out);
}

// Round 11
// 110.889 us; speedup vs baseline: 1.1458x; 1.1458x over previous
//
#include <hip/hip_runtime.h>
#include <math.h>

#define BSZ 4096
#define DIM 256
// 20 * log2(e): rows are pre-scaled by sqrt(20*log2e)/||row|| so the MFMA
// emits u = score*log2e; exp2(u - SC20L2E) == exp(score - 20) exactly.
#define SC20L2E 28.853900817779268f

#if __has_builtin(__builtin_amdgcn_exp2f)
#define EXP2F(x) __builtin_amdgcn_exp2f(x)
#else
#define EXP2F(x) exp2f(x)
#endif

typedef int   intx4    __attribute__((ext_vector_type(4)));
typedef int   intx8    __attribute__((ext_vector_type(8)));
typedef float floatx16 __attribute__((ext_vector_type(16)));

__device__ __forceinline__ void async_cp16(void* lds, const void* g) {
    __builtin_amdgcn_global_load_lds(
        (__attribute__((address_space(1))) unsigned int*)(unsigned long long)g,
        (__attribute__((address_space(3))) unsigned int*)lds,
        16, 0, 0);
}

// One wave per row index: load row r of all 4 matrices once.
// Outputs: fp8 e4m3 rows pre-scaled by sqrt(20*log2e)/||row||, fp32 diagonal
// scores for the 4 pairs; zeroes rowsum/colsum; inits out[0]=40 (const term).
__global__ __launch_bounds__(256)
void prep_kernel(const float* __restrict__ a0, const float* __restrict__ a1,
                 const float* __restrict__ a2, const float* __restrict__ a3,
                 unsigned char* __restrict__ f8, float* __restrict__ diag,
                 float* __restrict__ rowsum, float* __restrict__ colsum,
                 float* __restrict__ out) {
    const float* srcs[4] = {a0, a1, a2, a3};
    int w = threadIdx.x >> 6, lane = threadIdx.x & 63;
    int row = blockIdx.x * 4 + w;

    float4 v[4];
    float red[8];
    #pragma unroll
    for (int m = 0; m < 4; m++) {
        v[m] = ((const float4*)(srcs[m] + (size_t)row * DIM))[lane];
        red[m] = v[m].x * v[m].x + v[m].y * v[m].y + v[m].z * v[m].z + v[m].w * v[m].w;
    }
    // pair dots: (0,1) (0,2) (1,2) (1,3)
    red[4] = v[0].x * v[1].x + v[0].y * v[1].y + v[0].z * v[1].z + v[0].w * v[1].w;
    red[5] = v[0].x * v[2].x + v[0].y * v[2].y + v[0].z * v[2].z + v[0].w * v[2].w;
    red[6] = v[1].x * v[2].x + v[1].y * v[2].y + v[1].z * v[2].z + v[1].w * v[2].w;
    red[7] = v[1].x * v[3].x + v[1].y * v[3].y + v[1].z * v[3].z + v[1].w * v[3].w;

    #pragma unroll
    for (int i = 0; i < 8; i++) {
        #pragma unroll
        for (int s = 32; s; s >>= 1) red[i] += __shfl_xor(red[i], s, 64);
    }

    float rinv[4];
    #pragma unroll
    for (int m = 0; m < 4; m++) rinv[m] = rsqrtf(fmaxf(red[m], 1e-24f));

    const float sq = sqrtf(SC20L2E);
    #pragma unroll
    for (int m = 0; m < 4; m++) {
        float sc = sq * rinv[m];
        int pk = __builtin_amdgcn_cvt_pk_fp8_f32(v[m].x * sc, v[m].y * sc, 0, false);
        pk = __builtin_amdgcn_cvt_pk_fp8_f32(v[m].z * sc, v[m].w * sc, pk, true);
        ((unsigned int*)(f8 + (size_t)m * BSZ * DIM))[row * 64 + lane] = (unsigned int)pk;
    }

    if (lane == 0) {
        diag[0 * BSZ + row] = red[4] * 20.0f * rinv[0] * rinv[1];
        diag[1 * BSZ + row] = red[5] * 20.0f * rinv[0] * rinv[2];
        diag[2 * BSZ + row] = red[6] * 20.0f * rinv[1] * rinv[2];
        diag[3 * BSZ + row] = red[7] * 20.0f * rinv[1] * rinv[3];
    }
    if (blockIdx.x < 64) {
        int idx = blockIdx.x * 256 + threadIdx.x;
        rowsum[idx] = 0.f;
        colsum[idx] = 0.f;
        if (idx == 0) out[0] = 40.0f;   // + 20*4B/(2B) constant term
    }
}

// A-reuse streaming kernel: block (bi, jc, pair) computes FOUR 128x128 tiles
// (bj = jc*512 + t*128), staging the A panel once. Staged bytes: 1024 blocks
// x (32 KB A + 4 x 32 KB B) = 168 MB vs 268 MB for independent tiles -- the
// kernel is staging-BW bound (~6.2 TB/s effective from L2/fabric; FETCH_SIZE
// shows HBM is not touched).
// LDS 64 KB: A full-K (32 KB, 16-chunk XOR swizzle: slot=(c^row)&15) +
// B as 2 x 16 KB half-K double-buffer (paired-row swizzle:
// slot(row,c) = (row>>1)*16 + (row&1)*8 + ((c^(row>>1))&7) -> 2-way only).
// One barrier per half-K phase; next half-panel staged before compute so the
// barrier vmcnt-drain overlaps MFMA + epilogue. 2 blocks/CU.
// MX-scaled fp8 MFMA (unit E8M0 scales 0x7F): numerics identical to fp8.
// A/B operand layout (32x32x64): row = lane&31, k = (lane>>5)*32 + byte.
// C/D layout (32x32): col = lane&31, row = (reg&3)+8*(reg>>2)+4*(lane>>5).
// Row-sums accumulate in-register across the 4 tiles (one atomic at end).
// NOTE: no min-waves in launch_bounds (round 7: forced occupancy -> spill).
__global__ __launch_bounds__(256)
void pair_scores_kernel(const unsigned char* __restrict__ f8,
                        float* __restrict__ rowsum,
                        float* __restrict__ colsum) {
    const int PX[4] = {0, 0, 1, 1};
    const int PY[4] = {1, 2, 2, 3};
    int p = blockIdx.z;
    const unsigned char* Xb = f8 + (size_t)PX[p] * BSZ * DIM;
    const unsigned char* Yb = f8 + (size_t)PY[p] * BSZ * DIM;
    float* rs = rowsum + p * BSZ;
    float* cs = colsum + p * BSZ;

    __shared__ __align__(16) unsigned char smem[65536]; // A:0..32K, B:32K+buf*16K

    int tid  = threadIdx.x;
    int lane = tid & 63;
    int w    = tid >> 6;
    int wm = w >> 1, wn = w & 1;
    int l5 = lane & 31, h = lane >> 5;
    int bi  = blockIdx.x * 128;
    int bj0 = blockIdx.y * 512;

    // A fragment bases: addr = QA ^ (ph<<7) ^ (ks<<6) ^ (j<<4)
    unsigned QA[2];
    #pragma unroll
    for (int t = 0; t < 2; t++) {
        int ra = wm * 64 + t * 32 + l5;
        QA[t] = (unsigned)(ra * 256 + ((((h << 1) ^ ra) & 15) << 4));
    }
    // B fragment bases (within one 16 KB half-panel): addr = QB ^ (ks<<6) ^ (j<<4)
    unsigned QB[2];
    #pragma unroll
    for (int t = 0; t < 2; t++) {
        int rb = wn * 64 + t * 32 + l5;
        QB[t] = (unsigned)((rb >> 1) * 256 + (rb & 1) * 128
                           + ((((h << 1) ^ (rb >> 1)) & 7) << 4));
    }

    // B staging global offsets (per cp16 slot i, within a half-panel):
    // slot s: r2=s>>4, rlow=(s>>3)&1, cc=s&7 -> row=r2*2+rlow, c=(cc^r2)&7
    unsigned bOffG[4];
    #pragma unroll
    for (int i = 0; i < 4; i++) {
        int s = i * 256 + tid;
        int r2 = s >> 4, rlow = (s >> 3) & 1, c = ((s & 7) ^ r2) & 7;
        bOffG[i] = (unsigned)((r2 * 2 + rlow) * 256 + c * 16);
    }

    // ---- prologue: stage A (full-K, 32 KB) + B[tile0,half0] into buf0 ----
    #pragma unroll
    for (int i = 0; i < 8; i++) {
        int s = i * 256 + tid;
        int row = s >> 4, c = (s ^ row) & 15;
        async_cp16(smem + (i * 256 + w * 64) * 16,
                   Xb + (size_t)(bi + row) * 256 + c * 16);
    }
    {
        const unsigned char* yb = Yb + (size_t)bj0 * 256;
        #pragma unroll
        for (int i = 0; i < 4; i++)
            async_cp16(smem + 32768 + (i * 256 + w * 64) * 16, yb + bOffG[i]);
    }
    __syncthreads();

    floatx16 acc[2][2];
    #pragma unroll
    for (int i = 0; i < 2; i++)
        #pragma unroll
        for (int j = 0; j < 2; j++)
            #pragma unroll
            for (int r = 0; r < 16; r++)
                acc[i][j][r] = -SC20L2E;

    float rowacc = 0.f;

    #pragma unroll 1
    for (int gp = 0; gp < 8; gp++) {      // gp = tile*2 + half
        int t  = gp >> 1;
        int ph = gp & 1;

        if (gp < 7) {                      // stage next half-panel (other buf)
            int nt = (gp + 1) >> 1, np = (gp + 1) & 1;
            unsigned bufo = 32768u + (unsigned)(((gp + 1) & 1) * 16384);
            const unsigned char* yb = Yb + (size_t)(bj0 + nt * 128) * 256 + np * 128;
            #pragma unroll
            for (int i = 0; i < 4; i++)
                async_cp16(smem + bufo + (i * 256 + w * 64) * 16, yb + bOffG[i]);
        }

        // compute this half-K phase
        unsigned bbase = 32768u + (unsigned)((gp & 1) * 16384);
        unsigned pax = (unsigned)(ph << 7);
        #pragma unroll
        for (int ks = 0; ks < 2; ks++) {
            unsigned kx = (unsigned)(ks << 6);
            intx8 A[2], B[2];
            #pragma unroll
            for (int t2 = 0; t2 < 2; t2++) {
                unsigned a0 = QA[t2] ^ pax ^ kx;
                intx4 lo = *(const intx4*)(smem + a0);
                intx4 hi = *(const intx4*)(smem + (a0 ^ 16u));
                A[t2] = (intx8){lo[0], lo[1], lo[2], lo[3], hi[0], hi[1], hi[2], hi[3]};
                unsigned b0 = bbase + (QB[t2] ^ kx);
                intx4 bl = *(const intx4*)(smem + b0);
                intx4 bh = *(const intx4*)(smem + (b0 ^ 16u));
                B[t2] = (intx8){bl[0], bl[1], bl[2], bl[3], bh[0], bh[1], bh[2], bh[3]};
            }
            #pragma unroll
            for (int i = 0; i < 2; i++)
                #pragma unroll
                for (int j = 0; j < 2; j++)
                    acc[i][j] = __builtin_amdgcn_mfma_scale_f32_32x32x64_f8f6f4(
                        A[i], B[j], acc[i][j], 0, 0,
                        0, 0x7F7F7F7F, 0, 0x7F7F7F7F);
        }

        if (ph == 1) {
            // ---- tile epilogue (K complete): exp2, butterflies, sums ----
            int bjt = bj0 + t * 128;
            #pragma unroll
            for (int i = 0; i < 2; i++)
                #pragma unroll
                for (int j = 0; j < 2; j++)
                    #pragma unroll
                    for (int r = 0; r < 16; r++)
                        acc[i][j][r] = EXP2F(acc[i][j][r]);

            float v[32];
            #pragma unroll
            for (int t2 = 0; t2 < 2; t2++)
                #pragma unroll
                for (int r = 0; r < 16; r++)
                    v[t2 * 16 + r] = acc[t2][0][r] + acc[t2][1][r];

            float u1[16];
            #pragma unroll
            for (int k = 0; k < 16; k++) {
                float snd = (l5 & 1) ? v[2 * k] : v[2 * k + 1];
                float got = __shfl_xor(snd, 1, 64);
                u1[k] = ((l5 & 1) ? v[2 * k + 1] : v[2 * k]) + got;
            }
            float u2[8];
            #pragma unroll
            for (int k = 0; k < 8; k++) {
                float snd = ((l5 >> 1) & 1) ? u1[2 * k] : u1[2 * k + 1];
                float got = __shfl_xor(snd, 2, 64);
                u2[k] = (((l5 >> 1) & 1) ? u1[2 * k + 1] : u1[2 * k]) + got;
            }
            float u3[4];
            #pragma unroll
            for (int k = 0; k < 4; k++) {
                float snd = ((l5 >> 2) & 1) ? u2[2 * k] : u2[2 * k + 1];
                float got = __shfl_xor(snd, 4, 64);
                u3[k] = (((l5 >> 2) & 1) ? u2[2 * k + 1] : u2[2 * k]) + got;
            }
            float u4[2];
            #pragma unroll
            for (int k = 0; k < 2; k++) {
                float snd = ((l5 >> 3) & 1) ? u3[2 * k] : u3[2 * k + 1];
                float got = __shfl_xor(snd, 8, 64);
                u4[k] = (((l5 >> 3) & 1) ? u3[2 * k + 1] : u3[2 * k]) + got;
            }
            {
                float snd = ((l5 >> 4) & 1) ? u4[0] : u4[1];
                float got = __shfl_xor(snd, 16, 64);
                rowacc += (((l5 >> 4) & 1) ? u4[1] : u4[0]) + got;
            }

            float c0 = 0.f, c1 = 0.f;
            #pragma unroll
            for (int t2 = 0; t2 < 2; t2++)
                #pragma unroll
                for (int r = 0; r < 16; r++) {
                    c0 += acc[t2][0][r];
                    c1 += acc[t2][1][r];
                }
            {
                float snd = h ? c0 : c1;
                float got = __shfl_xor(snd, 32, 64);
                float cc = (h ? c1 : c0) + got;
                atomicAdd(&cs[bjt + wn * 64 + h * 32 + l5], cc);
            }

            // reset accumulators for next tile
            #pragma unroll
            for (int i = 0; i < 2; i++)
                #pragma unroll
                for (int j = 0; j < 2; j++)
                    #pragma unroll
                    for (int r = 0; r < 16; r++)
                        acc[i][j][r] = -SC20L2E;
        }

        __syncthreads();   // drains next-half staging; guards buffer reuse
    }

    // one row atomic per lane (4 tiles accumulated)
    {
        int reg = l5 & 15;
        int row = bi + wm * 64 + (l5 >> 4) * 32
                + (reg & 3) + 8 * (reg >> 2) + 4 * h;
        atomicAdd(&rs[row], rowacc);
    }
}

// 64 blocks: each thread one (pair,row) entry; wave-reduce then atomicAdd
// into out (prep pre-set out = 40, the 20*4B/(2B) constant).
__global__ __launch_bounds__(256)
void final_reduce_kernel(const float* __restrict__ rowsum,
                         const float* __restrict__ colsum,
                         const float* __restrict__ diag,
                         float* __restrict__ out) {
    int idx = blockIdx.x * 256 + threadIdx.x;
    float acc = 0.5f * (__logf(rowsum[idx]) + __logf(colsum[idx])) - diag[idx];
    #pragma unroll
    for (int s = 32; s; s >>= 1) acc += __shfl_xor(acc, s, 64);
    if ((threadIdx.x & 63) == 0)
        atomicAdd(out, acc * (1.0f / (2.0f * BSZ)));
}

extern "C" void kernel_launch(void* const* d_in, const int* in_sizes, int n_in,
                              void* d_out, int out_size, void* d_ws, size_t ws_size,
                              hipStream_t stream) {
    const float* in_anchor = (const float*)d_in[0];
    const float* in_pos    = (const float*)d_in[1];
    // d_in[2] (reference_anchor) intentionally unused, matching the reference.
    const float* in_rtext  = (const float*)d_in[3];
    const float* in_rvis   = (const float*)d_in[4];

    char* ws = (char*)d_ws;
    unsigned char* f8 = (unsigned char*)ws;                 // 4 * B * D fp8
    size_t f8_bytes = (size_t)4 * BSZ * DIM;
    float* rowsum = (float*)(ws + f8_bytes);                // 4 * B
    float* colsum = rowsum + 4 * BSZ;                       // 4 * B
    float* diag   = colsum + 4 * BSZ;                       // 4 * B

    prep_kernel<<<BSZ / 4, 256, 0, stream>>>(
        in_anchor, in_pos, in_rtext, in_rvis, f8, diag, rowsum, colsum,
        (float*)d_out);

    pair_scores_kernel<<<dim3(BSZ / 128, 8, 4), 256, 0, stream>>>(
        f8, rowsum, colsum);

    final_reduce_kernel<<<64, 256, 0, stream>>>(
        rowsum, colsum, diag, (float*)d_out);
}